// Round 14
// baseline (263.418 us; speedup 1.0000x reference)
//
#include <hip/hip_runtime.h>
#include <stdint.h>

#define DEV __device__ __forceinline__

typedef uint16_t u16;
typedef __attribute__((ext_vector_type(8))) short short8;
typedef __attribute__((ext_vector_type(4))) float f32x4;
typedef __attribute__((ext_vector_type(8))) __bf16 bf16x8;
typedef __attribute__((ext_vector_type(4))) int int4v;
typedef __attribute__((ext_vector_type(2))) unsigned int u32x2;
typedef __attribute__((ext_vector_type(4))) short s16x4;

static constexpr int Bn = 4, Sn = 2048, Dn = 768, Hn = 12, DFFn = 3072;
static constexpr int BS = Bn * Sn;   // 8192 tokens
static constexpr float EPS = 1e-6f;
static constexpr float C1 = 0.18033688011112042f;   // 0.125 * log2(e)
static constexpr float SHIFT = 11.541560327111707f; // 8 * log2(e)

DEV u16 f2bf(float f) {
  union { float f; uint32_t u; } cv; cv.f = f;
  uint32_t u = cv.u;
  u += 0x7FFFu + ((u >> 16) & 1u);   // round-to-nearest-even
  return (u16)(u >> 16);
}

DEV uint32_t pk_bf16(float a, float b) {
  union { __bf16 h[2]; uint32_t u; } cv;
  cv.h[0] = (__bf16)a; cv.h[1] = (__bf16)b;
  return cv.u;
}

DEV float exp2_raw(float x) {
  float r;
  asm("v_exp_f32 %0, %1" : "=v"(r) : "v"(x));
  return r;
}

DEV float bf2f(u16 v) {
  union { uint32_t u; float f; } cv; cv.u = (uint32_t)v << 16;
  return cv.f;
}

DEV f32x4 mfma16(short8 a, short8 b, f32x4 c) {
  return __builtin_amdgcn_mfma_f32_16x16x32_bf16(
      __builtin_bit_cast(bf16x8, a), __builtin_bit_cast(bf16x8, b), c, 0, 0, 0);
}

DEV void glds16(const void* g, void* l) {
  __builtin_amdgcn_global_load_lds(
      (const __attribute__((address_space(1))) void*)g,
      (__attribute__((address_space(3))) void*)l, 16, 0, 0);
}

DEV void barf() {
  asm volatile("" ::: "memory");
  __builtin_amdgcn_s_barrier();
  asm volatile("" ::: "memory");
}
#define WAITV(n) asm volatile("s_waitcnt vmcnt(" #n ")" ::: "memory")

// inverse of slot u = (r*4 + s) ^ (r&7); valid for r < 256
DEV void inv_swz(int u, int& r, int& s) {
  r = ((u >> 2) & 0x1FE) | (((u >> 2) ^ (u >> 4)) & 1);
  s = ((u ^ (u >> 2) ^ (u >> 4)) & 1) | ((u ^ (u >> 2)) & 2);
}

// ---------------- fused prep: x->bf16 + all weight transposes ----------------

__global__ __launch_bounds__(256)
void prep_kernel(const float* __restrict__ x,
                 const float* __restrict__ wq, const float* __restrict__ wk,
                 const float* __restrict__ wv, const float* __restrict__ wo,
                 const float* __restrict__ w1, const float* __restrict__ w2,
                 u16* __restrict__ xb, u16* __restrict__ wqkvT,
                 u16* __restrict__ w1T, u16* __restrict__ w2T) {
  const int bid = blockIdx.x;
  const int tid = threadIdx.x;
  if (bid < 3072) {
    size_t i = (size_t)bid * 256 + tid;
    const f32x4* p = (const f32x4*)x + i * 2;
    f32x4 a = p[0], b = p[1];
    short8 o;
    o[0] = (short)f2bf(a[0]); o[1] = (short)f2bf(a[1]);
    o[2] = (short)f2bf(a[2]); o[3] = (short)f2bf(a[3]);
    o[4] = (short)f2bf(b[0]); o[5] = (short)f2bf(b[1]);
    o[6] = (short)f2bf(b[2]); o[7] = (short)f2bf(b[3]);
    *(short8*)(xb + i * 8) = o;
    return;
  }
  __shared__ float T[32][33];
  const float* w; u16* o; int K, N, bx, by;
  float scale = 1.f;
  if (bid < 5376) {
    int q = bid - 3072;
    int z = q / 576; q -= z * 576;
    w = (z == 0) ? wq : (z == 1) ? wk : (z == 2) ? wv : wo;
    o = wqkvT + (size_t)z * Dn * Dn;
    K = Dn; N = Dn;
    scale = (z == 0) ? C1 : 1.f;
    bx = q % 24; by = q / 24;
  } else if (bid < 7680) {
    int q = bid - 5376;
    w = w1; o = w1T; K = Dn; N = DFFn;
    bx = q % 96; by = q / 96;
  } else {
    int q = bid - 7680;
    w = w2; o = w2T; K = DFFn; N = Dn;
    bx = q % 24; by = q / 24;
  }
  const int tx = tid & 31, ty = tid >> 5;
  const int n0 = bx * 32, k0 = by * 32;
#pragma unroll
  for (int i = 0; i < 4; ++i)
    T[ty + 8 * i][tx] = w[(size_t)(k0 + ty + 8 * i) * N + n0 + tx];
  __syncthreads();
#pragma unroll
  for (int i = 0; i < 4; ++i)
    o[(size_t)(n0 + ty + 8 * i) * K + k0 + tx] = f2bf(T[tx][ty + 8 * i] * scale);
}

// ==== GEMM BMx128, BK=32, 1 barrier/tile ====================================
// BM=256: 2 LDS buffers (48KB -> 3 blocks/CU, zero-tail grids), vmcnt(0)/tile.
// BM=128: 3 LDS buffers, depth-2 prefetch, counted vmcnt (grid all-resident).
// VFUSE: qkv V tiles (col0 >= 1536) written transposed to vt[bh][dk][S].
// RES: 0 none, 1 add fp32 residual, 2 add bf16 residual.

template<int BM, bool OUT_BF16, bool RELU, bool HAS_BIAS, bool VFUSE, int RES>
__global__ __launch_bounds__(BM * 2, 4)
void gemm_kernel(const u16* __restrict__ A, const u16* __restrict__ Bt,
                 const float* __restrict__ bias, void* __restrict__ Cout,
                 int N, int K, int gx, u16* __restrict__ vt,
                 const void* __restrict__ resid) {
  constexpr int ABYTES = BM * 64;          // A bytes per buffer (BM x 32 bf16)
  constexpr int BUFSZ = ABYTES + 8192;     // + B (128 x 32 bf16)
  constexpr int NBUF = (BM == 256) ? 2 : 3;
  __shared__ char lds[NBUF * BUFSZ];
  const int tid = threadIdx.x;
  const int wave = tid >> 6, lane = tid & 63;
  const int lr = lane & 15, lg = lane >> 4;
  const int wr = wave >> 1, wc = wave & 1;

  const int kk = blockIdx.x >> 3, xcd = blockIdx.x & 7;
  const int row0 = (xcd + 8 * (kk / gx)) * BM, col0 = (kk % gx) * 128;

  size_t aofs[2], bofs[2];
#pragma unroll
  for (int i = 0; i < 2; ++i) {
    int r, s;
    inv_swz(tid + i * (BM * 2), r, s);
    aofs[i] = (size_t)(row0 + r) * K + s * 8;
  }
  {
    int r, s;
    inv_swz(tid, r, s);
    bofs[0] = (size_t)(col0 + r) * K + s * 8;
    if (BM == 128) {
      inv_swz(tid + 256, r, s);
      bofs[1] = (size_t)(col0 + r) * K + s * 8;
    }
  }
  const int aD0 = wave * 1024, aD1 = BM * 32 + wave * 1024;

  int aB[4], bB[4];
#pragma unroll
  for (int mi = 0; mi < 4; ++mi) {
    int row = wr * 64 + mi * 16 + lr;
    aB[mi] = ((row << 6) | (lg << 4)) ^ ((row & 7) << 4);
  }
#pragma unroll
  for (int nj = 0; nj < 4; ++nj) {
    int row = wc * 64 + nj * 16 + lr;
    bB[nj] = ((row << 6) | (lg << 4)) ^ ((row & 7) << 4);
  }

  f32x4 acc[4][4];
#pragma unroll
  for (int i = 0; i < 4; ++i)
#pragma unroll
    for (int j = 0; j < 4; ++j) acc[i][j] = (f32x4){0.f, 0.f, 0.f, 0.f};

  const int NT = K >> 5;
  auto stage = [&](char* buf, int kb) {
    glds16(A + aofs[0] + kb, buf + aD0);
    glds16(A + aofs[1] + kb, buf + aD1);
    glds16(Bt + bofs[0] + kb, buf + ABYTES + wave * 1024);
    if (BM == 128)
      glds16(Bt + bofs[1] + kb, buf + ABYTES + 4096 + wave * 1024);
  };

  auto compute = [&](char* b0) {
    short8 a_[4], b_[4];
#pragma unroll
    for (int mi = 0; mi < 4; ++mi)
      a_[mi] = *(const short8*)(b0 + aB[mi]);
#pragma unroll
    for (int nj = 0; nj < 4; ++nj)
      b_[nj] = *(const short8*)(b0 + ABYTES + bB[nj]);
    __builtin_amdgcn_s_setprio(1);
#pragma unroll
    for (int mi = 0; mi < 4; ++mi)
#pragma unroll
      for (int nj = 0; nj < 4; ++nj)
        acc[mi][nj] = mfma16(a_[mi], b_[nj], acc[mi][nj]);
    __builtin_amdgcn_s_setprio(0);
  };

  if (BM == 256) {
    // 2-buffer: stage issued AFTER the tile-top barrier; full drain per tile
    char* b0 = lds;
    char* b1 = lds + BUFSZ;
    stage(b0, 0);
    for (int t = 0; t < NT; ++t) {
      WAITV(0);
      barf();
      if (t + 1 < NT) stage(b1, (t + 1) * 32);
      compute(b0);
      char* tmp = b0; b0 = b1; b1 = tmp;
    }
  } else {
    // 3-buffer depth-2 prefetch with counted vmcnt
    char* b0 = lds;
    char* b1 = lds + BUFSZ;
    char* b2 = lds + 2 * BUFSZ;
    stage(b0, 0);
    stage(b1, 32);
    for (int t = 0; t < NT; ++t) {
      if (t < NT - 1) { WAITV(4); } else { WAITV(0); }
      barf();
      if (t + 2 < NT) stage(b2, (t + 2) * 32);
      compute(b0);
      char* tmp = b0; b0 = b1; b1 = b2; b2 = tmp;
    }
  }

  if (VFUSE && col0 >= 1536) {
#pragma unroll
    for (int mi = 0; mi < 4; ++mi) {
      int row = row0 + wr * 64 + mi * 16 + lg * 4;
      int b = row >> 11, s = row & 2047;
#pragma unroll
      for (int nj = 0; nj < 4; ++nj) {
        int col = col0 + wc * 64 + nj * 16 + lr;
        int bh = b * Hn + ((col - 1536) >> 6), dk = col & 63;
        s16x4 v;
#pragma unroll
        for (int r = 0; r < 4; ++r) v[r] = (short)f2bf(acc[mi][nj][r]);
        *(s16x4*)(vt + (size_t)(bh * 64 + dk) * Sn + s) = v;
      }
    }
    return;
  }

#pragma unroll
  for (int mi = 0; mi < 4; ++mi) {
    int row = row0 + wr * 64 + mi * 16 + lg * 4;
#pragma unroll
    for (int nj = 0; nj < 4; ++nj) {
      int col = col0 + wc * 64 + nj * 16 + lr;
      float bv = HAS_BIAS ? bias[col] : 0.f;
#pragma unroll
      for (int r = 0; r < 4; ++r) {
        float v = acc[mi][nj][r] + bv;
        size_t o = (size_t)(row + r) * N + col;
        if (RES == 1) v += ((const float*)resid)[o];
        if (RES == 2) v += bf2f(((const u16*)resid)[o]);
        if (RELU) v = fmaxf(v, 0.f);
        if (OUT_BF16) ((u16*)Cout)[o] = f2bf(v);
        else ((float*)Cout)[o] = v;
      }
    }
  }
}

// ---------------- flash attention (R10 structure + T5 setprio) -------------
// 128 q-rows/block; static-shift softmax; K/V fragments read once per tile;
// l on the matrix pipe (MFMA vs all-ones).

__global__ __launch_bounds__(256, 3)
void attn_kernel(const u16* __restrict__ qkv, const u16* __restrict__ vt,
                 const int* __restrict__ mask, u16* __restrict__ ctx) {
  __shared__ u16 kbuf[2][4096];
  __shared__ u16 vbuf[2][4096];
  __shared__ u16 pbuf[4][2][1024];

  const int tid = threadIdx.x;
  const int wave = tid >> 6, lane = tid & 63;
  const int lr = lane & 15, lg = lane >> 4;

  const int lin = blockIdx.x;
  const int logical = (lin & 7) * 96 + (lin >> 3);
  const int qt = logical & 15;
  const int bh = logical >> 4;
  const int b = bh / Hn, h = bh % Hn;

  int ok;
  {
    const int4v* ms = (const int4v*)(mask + b * Sn);
    int4v m0 = ms[tid * 2], m1 = ms[tid * 2 + 1];
    ok = m0[0] && m0[1] && m0[2] && m0[3] && m1[0] && m1[1] && m1[2] && m1[3];
  }
  const bool allones = (__syncthreads_and(ok) != 0);

  const int cu = (lane & 7) ^ (lane >> 3);
  const int r0 = wave * 16 + (lane >> 3);
  const u16* kg0 = qkv + (size_t)(b * Sn + r0) * 2304 + 768 + h * 64 + cu * 8;
  const u16* vg0 = vt + (size_t)(bh * 64 + r0) * Sn + cu * 8;
  u16* kd = &kbuf[0][0] + wave * 1024;
  u16* vd = &vbuf[0][0] + wave * 1024;

  const size_t qrowA = (size_t)(b * Sn + qt * 128 + wave * 16 + lr) * 2304 + h * 64 + lg * 8;
  short8 qa0 = *(const short8*)(qkv + qrowA);
  short8 qa1 = *(const short8*)(qkv + qrowA + 32);
  const size_t qrowB = qrowA + (size_t)64 * 2304;
  short8 qb0 = *(const short8*)(qkv + qrowB);
  short8 qb1 = *(const short8*)(qkv + qrowB + 32);

  short8 ones;
#pragma unroll
  for (int j = 0; j < 8; ++j) ones[j] = (short)0x3F80;   // bf16 1.0

  const int rlo = (lg ^ (lr & 7)) << 4;
  const int rhi = ((4 + lg) ^ (lr & 7)) << 4;
  const int rowb = lr * 128;

  f32x4 caccA[4], caccB[4], laccA, laccB;
#pragma unroll
  for (int i = 0; i < 4; ++i) {
    caccA[i] = (f32x4){0.f, 0.f, 0.f, 0.f};
    caccB[i] = (f32x4){0.f, 0.f, 0.f, 0.f};
  }
  laccA = (f32x4){0.f, 0.f, 0.f, 0.f};
  laccB = (f32x4){0.f, 0.f, 0.f, 0.f};

  u16* pwA = &pbuf[wave][0][0];
  u16* pwB = &pbuf[wave][1][0];
  const int pwr = (lg >> 1), pwo = 8 * (lg & 1);

  auto stage = [&](int bf, int c) {
    const u16* kg = kg0 + (size_t)c * 64 * 2304;
    const u16* vg = vg0 + c * 64;
    glds16(kg,            kd + bf * 4096);
    glds16(kg + 8 * 2304, kd + bf * 4096 + 512);
    glds16(vg,            vd + bf * 4096);
    glds16(vg + 8 * Sn,   vd + bf * 4096 + 512);
  };

  stage(0, 0);
  __syncthreads();
  int cur = 0;
  for (int c = 0; c < 32; ++c) {
    if (c + 1 < 32) stage(cur ^ 1, c + 1);
    const char* kb = (const char*)&kbuf[cur][0];
    const char* vb = (const char*)&vbuf[cur][0];

    int4v mk[4];
    if (!allones) {
      const int4v* mp = (const int4v*)(mask + b * Sn + c * 64 + lg * 4);
#pragma unroll
      for (int f = 0; f < 4; ++f) mk[f] = mp[f * 4];
    }

    // QK^T both q-sets, each K fragment read once
    f32x4 scA[4], scB[4];
    __builtin_amdgcn_s_setprio(1);
#pragma unroll
    for (int f = 0; f < 4; ++f) {
      short8 k0 = *(const short8*)(kb + f * 2048 + rowb + rlo);
      short8 k1 = *(const short8*)(kb + f * 2048 + rowb + rhi);
      f32x4 zA = (f32x4){-SHIFT, -SHIFT, -SHIFT, -SHIFT};
      zA = mfma16(k0, qa0, zA);
      zA = mfma16(k1, qa1, zA);
      scA[f] = zA;
      f32x4 zB = (f32x4){-SHIFT, -SHIFT, -SHIFT, -SHIFT};
      zB = mfma16(k0, qb0, zB);
      zB = mfma16(k1, qb1, zB);
      scB[f] = zB;
    }
    __builtin_amdgcn_s_setprio(0);
    if (!allones) {
#pragma unroll
      for (int f = 0; f < 4; ++f)
#pragma unroll
        for (int r = 0; r < 4; ++r) {
          scA[f][r] = mk[f][r] ? scA[f][r] : -1.0e5f;
          scB[f][r] = mk[f][r] ? scB[f][r] : -1.0e5f;
        }
    }
#pragma unroll
    for (int f = 0; f < 4; ++f) {
#pragma unroll
      for (int r = 0; r < 4; ++r) {
        scA[f][r] = exp2_raw(scA[f][r]);
        scB[f][r] = exp2_raw(scB[f][r]);
      }
    }
    // P -> bf16 -> per-wave swizzled LDS (both sets), then read fragments
#pragma unroll
    for (int f = 0; f < 4; ++f) {
      u32x2 wA, wB;
      wA[0] = pk_bf16(scA[f][0], scA[f][1]);
      wA[1] = pk_bf16(scA[f][2], scA[f][3]);
      wB[0] = pk_bf16(scB[f][0], scB[f][1]);
      wB[1] = pk_bf16(scB[f][2], scB[f][3]);
      const int po = rowb + (((2 * f + pwr) ^ (lr & 7)) << 4) + pwo;
      *(u32x2*)((char*)pwA + po) = wA;
      *(u32x2*)((char*)pwB + po) = wB;
    }
    short8 pfA0 = *(const short8*)((const char*)pwA + rowb + rlo);
    short8 pfA1 = *(const short8*)((const char*)pwA + rowb + rhi);
    short8 pfB0 = *(const short8*)((const char*)pwB + rowb + rlo);
    short8 pfB1 = *(const short8*)((const char*)pwB + rowb + rhi);

    // PV both q-sets, each V fragment read once
    __builtin_amdgcn_s_setprio(1);
#pragma unroll
    for (int fd = 0; fd < 4; ++fd) {
      short8 v0 = *(const short8*)(vb + fd * 2048 + rowb + rlo);
      short8 v1 = *(const short8*)(vb + fd * 2048 + rowb + rhi);
      caccA[fd] = mfma16(pfA0, v0, caccA[fd]);
      caccA[fd] = mfma16(pfA1, v1, caccA[fd]);
      caccB[fd] = mfma16(pfB0, v0, caccB[fd]);
      caccB[fd] = mfma16(pfB1, v1, caccB[fd]);
    }
    // l row-sums on the matrix pipe (B = ones)
    laccA = mfma16(pfA0, ones, laccA);
    laccA = mfma16(pfA1, ones, laccA);
    laccB = mfma16(pfB0, ones, laccB);
    laccB = mfma16(pfB1, ones, laccB);
    __builtin_amdgcn_s_setprio(0);
    __syncthreads();
    cur ^= 1;
  }

  float linvA[4], linvB[4];
#pragma unroll
  for (int r = 0; r < 4; ++r) {
    linvA[r] = 1.0f / laccA[r];
    linvB[r] = 1.0f / laccB[r];
  }
  const int orow = b * Sn + qt * 128 + wave * 16 + lg * 4;
#pragma unroll
  for (int fd = 0; fd < 4; ++fd) {
    int col = h * 64 + fd * 16 + lr;
#pragma unroll
    for (int r = 0; r < 4; ++r) {
      ctx[(size_t)(orow + r) * Dn + col] = f2bf(caccA[fd][r] * linvA[r]);
      ctx[(size_t)(orow + 64 + r) * Dn + col] = f2bf(caccB[fd][r] * linvB[r]);
    }
  }
}

// ---- LayerNorm: one wave per row; ASRC: 0=fp32 1=bf16 input ---------------

template<int ASRC>
__global__ __launch_bounds__(256)
void ln_kernel(const void* __restrict__ a,
               const float* __restrict__ alpha, const float* __restrict__ beta,
               float* __restrict__ outf, u16* __restrict__ outb) {
  const int wave = threadIdx.x >> 6, lane = threadIdx.x & 63;
  const size_t base = ((size_t)blockIdx.x * 4 + wave) * Dn;
  const int o = lane * 4;
  f32x4 v[3];
  float s = 0.f, q = 0.f;
#pragma unroll
  for (int j = 0; j < 3; ++j) {
    f32x4 x;
    if (ASRC == 0) {
      x = *(const f32x4*)((const float*)a + base + j * 256 + o);
    } else {
      s16x4 bb = *(const s16x4*)((const u16*)a + base + j * 256 + o);
#pragma unroll
      for (int k = 0; k < 4; ++k) x[k] = bf2f((u16)bb[k]);
    }
    v[j] = x;
    s += (x[0] + x[1]) + (x[2] + x[3]);
    q += (x[0] * x[0] + x[1] * x[1]) + (x[2] * x[2] + x[3] * x[3]);
  }
#pragma unroll
  for (int sh = 1; sh < 64; sh <<= 1) {
    s += __shfl_xor(s, sh, 64);
    q += __shfl_xor(q, sh, 64);
  }
  const float mean = s * (1.f / 768.f);
  float var = (q - 768.f * mean * mean) * (1.f / 767.f);
  var = fmaxf(var, 0.f);
  const float rden = 1.f / (sqrtf(var) + EPS);
#pragma unroll
  for (int j = 0; j < 3; ++j) {
    f32x4 al = *(const f32x4*)(alpha + j * 256 + o);
    f32x4 be = *(const f32x4*)(beta + j * 256 + o);
    f32x4 y;
#pragma unroll
    for (int k = 0; k < 4; ++k)
      y[k] = al[k] * (v[j][k] - mean) * rden + be[k];
    if (outf) *(f32x4*)(outf + base + j * 256 + o) = y;
    if (outb) {
      u32x2 w;
      w[0] = pk_bf16(y[0], y[1]);
      w[1] = pk_bf16(y[2], y[3]);
      *(u32x2*)(outb + base + j * 256 + o) = w;
    }
  }
}

// ---------------- launch ----------------

extern "C" void kernel_launch(void* const* d_in, const int* in_sizes, int n_in,
                              void* d_out, int out_size, void* d_ws, size_t ws_size,
                              hipStream_t stream) {
  (void)in_sizes; (void)n_in; (void)out_size; (void)ws_size;
  const float* x    = (const float*)d_in[0];
  const int*   mask = (const int*)d_in[1];
  const float* wq   = (const float*)d_in[2];
  const float* wk   = (const float*)d_in[3];
  const float* wv   = (const float*)d_in[4];
  const float* wo   = (const float*)d_in[5];
  const float* w1   = (const float*)d_in[6];
  const float* b1   = (const float*)d_in[7];
  const float* w2   = (const float*)d_in[8];
  const float* b2   = (const float*)d_in[9];
  const float* ln1a = (const float*)d_in[10];
  const float* ln1b = (const float*)d_in[11];
  const float* ln2a = (const float*)d_in[12];
  const float* ln2b = (const float*)d_in[13];
  float* out = (float*)d_out;

  char* ws = (char*)d_ws;
  size_t off = 0;
  auto alloc = [&](size_t bytes) -> void* {
    void* p = ws + off;
    off += (bytes + 255) & ~(size_t)255;
    return p;
  };
  u16* xb    = (u16*)alloc((size_t)BS * Dn * 2);      // reused as ctx later
  u16* wqkvT = (u16*)alloc((size_t)2304 * Dn * 2);
  u16* woT   = (u16*)alloc((size_t)Dn * Dn * 2);      // contiguous after wqkvT
  u16* w1T   = (u16*)alloc((size_t)DFFn * Dn * 2);
  u16* w2T   = (u16*)alloc((size_t)Dn * DFFn * 2);
  u16* qkv   = (u16*)alloc((size_t)BS * 2304 * 2);
  u16* vt    = (u16*)alloc((size_t)48 * 64 * Sn * 2);
  u16* x1b   = (u16*)alloc((size_t)BS * Dn * 2);
  u16* ff1   = (u16*)alloc((size_t)BS * DFFn * 2);
  u16* y16   = (u16*)alloc((size_t)BS * Dn * 2);      // bf16 LN inputs
  u16* ctx   = xb;
  (void)woT;

  dim3 blk256(256), blk512(512);
  prep_kernel<<<dim3(9984), blk256, 0, stream>>>(x, wq, wk, wv, wo, w1, w2,
                                                 xb, wqkvT, w1T, w2T);

  // qkv = xb @ [wq'|wk|wv]; V tiles fused-transposed into vt
  gemm_kernel<256, true, false, false, true, 0><<<dim3(576), blk512, 0, stream>>>(xb, wqkvT, nullptr, qkv, 2304, 768, 18, vt, nullptr);
  attn_kernel<<<dim3(768), blk256, 0, stream>>>(qkv, vt, mask, ctx);
  // y16 = bf16(ctx @ wo + x)   (residual fused, bf16 out)
  gemm_kernel<128, true, false, false, false, 1><<<dim3(384), blk256, 0, stream>>>(ctx, wqkvT + 3 * Dn * Dn, nullptr, y16, 768, 768, 6, nullptr, x);
  // x1 = LN(y16) -> bf16
  ln_kernel<1><<<dim3(BS / 4), blk256, 0, stream>>>(y16, ln1a, ln1b, nullptr, x1b);
  // ff1 = relu(x1 @ w1 + b1)
  gemm_kernel<256, true, true, true, false, 0><<<dim3(768), blk512, 0, stream>>>(x1b, w1T, b1, ff1, 3072, 768, 24, nullptr, nullptr);
  // y16 = bf16(ff1 @ w2 + b2 + x1)   (residual fused, bf16 out)
  gemm_kernel<128, true, false, true, false, 2><<<dim3(384), blk256, 0, stream>>>(ff1, w2T, b2, y16, 768, 3072, 6, nullptr, x1b);
  // out = LN(y16)
  ln_kernel<1><<<dim3(BS / 4), blk256, 0, stream>>>(y16, ln2a, ln2b, out, nullptr);
}

// Round 15
// 257.784 us; speedup vs baseline: 1.0219x; 1.0219x over previous
//
#include <hip/hip_runtime.h>
#include <stdint.h>

#define DEV __device__ __forceinline__

typedef uint16_t u16;
typedef __attribute__((ext_vector_type(8))) short short8;
typedef __attribute__((ext_vector_type(4))) float f32x4;
typedef __attribute__((ext_vector_type(8))) __bf16 bf16x8;
typedef __attribute__((ext_vector_type(4))) int int4v;
typedef __attribute__((ext_vector_type(2))) unsigned int u32x2;
typedef __attribute__((ext_vector_type(4))) short s16x4;

static constexpr int Bn = 4, Sn = 2048, Dn = 768, Hn = 12, DFFn = 3072;
static constexpr int BS = Bn * Sn;   // 8192 tokens
static constexpr float EPS = 1e-6f;
static constexpr float C1 = 0.18033688011112042f;   // 0.125 * log2(e)
static constexpr float SHIFT = 11.541560327111707f; // 8 * log2(e)

DEV u16 f2bf(float f) {
  union { float f; uint32_t u; } cv; cv.f = f;
  uint32_t u = cv.u;
  u += 0x7FFFu + ((u >> 16) & 1u);   // round-to-nearest-even
  return (u16)(u >> 16);
}

DEV uint32_t pk_bf16(float a, float b) {
  union { __bf16 h[2]; uint32_t u; } cv;
  cv.h[0] = (__bf16)a; cv.h[1] = (__bf16)b;
  return cv.u;
}

DEV float exp2_raw(float x) {
  float r;
  asm("v_exp_f32 %0, %1" : "=v"(r) : "v"(x));
  return r;
}

DEV float bf2f(u16 v) {
  union { uint32_t u; float f; } cv; cv.u = (uint32_t)v << 16;
  return cv.f;
}

DEV f32x4 mfma16(short8 a, short8 b, f32x4 c) {
  return __builtin_amdgcn_mfma_f32_16x16x32_bf16(
      __builtin_bit_cast(bf16x8, a), __builtin_bit_cast(bf16x8, b), c, 0, 0, 0);
}

DEV void glds16(const void* g, void* l) {
  __builtin_amdgcn_global_load_lds(
      (const __attribute__((address_space(1))) void*)g,
      (__attribute__((address_space(3))) void*)l, 16, 0, 0);
}

DEV void barf() {
  asm volatile("" ::: "memory");
  __builtin_amdgcn_s_barrier();
  asm volatile("" ::: "memory");
}
#define WAITV(n) asm volatile("s_waitcnt vmcnt(" #n ")" ::: "memory")

// inverse of slot u = (r*4 + s) ^ (r&7); valid for r < 256
DEV void inv_swz(int u, int& r, int& s) {
  r = ((u >> 2) & 0x1FE) | (((u >> 2) ^ (u >> 4)) & 1);
  s = ((u ^ (u >> 2) ^ (u >> 4)) & 1) | ((u ^ (u >> 2)) & 2);
}

// ---------------- fused prep: x->bf16 + all weight transposes ----------------

__global__ __launch_bounds__(256)
void prep_kernel(const float* __restrict__ x,
                 const float* __restrict__ wq, const float* __restrict__ wk,
                 const float* __restrict__ wv, const float* __restrict__ wo,
                 const float* __restrict__ w1, const float* __restrict__ w2,
                 u16* __restrict__ xb, u16* __restrict__ wqkvT,
                 u16* __restrict__ w1T, u16* __restrict__ w2T) {
  const int bid = blockIdx.x;
  const int tid = threadIdx.x;
  if (bid < 3072) {
    size_t i = (size_t)bid * 256 + tid;
    const f32x4* p = (const f32x4*)x + i * 2;
    f32x4 a = p[0], b = p[1];
    short8 o;
    o[0] = (short)f2bf(a[0]); o[1] = (short)f2bf(a[1]);
    o[2] = (short)f2bf(a[2]); o[3] = (short)f2bf(a[3]);
    o[4] = (short)f2bf(b[0]); o[5] = (short)f2bf(b[1]);
    o[6] = (short)f2bf(b[2]); o[7] = (short)f2bf(b[3]);
    *(short8*)(xb + i * 8) = o;
    return;
  }
  __shared__ float T[32][33];
  const float* w; u16* o; int K, N, bx, by;
  float scale = 1.f;
  if (bid < 5376) {
    int q = bid - 3072;
    int z = q / 576; q -= z * 576;
    w = (z == 0) ? wq : (z == 1) ? wk : (z == 2) ? wv : wo;
    o = wqkvT + (size_t)z * Dn * Dn;
    K = Dn; N = Dn;
    scale = (z == 0) ? C1 : 1.f;
    bx = q % 24; by = q / 24;
  } else if (bid < 7680) {
    int q = bid - 5376;
    w = w1; o = w1T; K = Dn; N = DFFn;
    bx = q % 96; by = q / 96;
  } else {
    int q = bid - 7680;
    w = w2; o = w2T; K = DFFn; N = Dn;
    bx = q % 24; by = q / 24;
  }
  const int tx = tid & 31, ty = tid >> 5;
  const int n0 = bx * 32, k0 = by * 32;
#pragma unroll
  for (int i = 0; i < 4; ++i)
    T[ty + 8 * i][tx] = w[(size_t)(k0 + ty + 8 * i) * N + n0 + tx];
  __syncthreads();
#pragma unroll
  for (int i = 0; i < 4; ++i)
    o[(size_t)(n0 + ty + 8 * i) * K + k0 + tx] = f2bf(T[tx][ty + 8 * i] * scale);
}

// ==== GEMM BMx128, BK=32, depth-2 prefetch (3 LDS buffers), 1 barrier/tile ===

template<int BM, bool OUT_BF16, bool RELU, bool HAS_BIAS, bool VFUSE, int RES>
__global__ __launch_bounds__(BM * 2, 4)
void gemm_kernel(const u16* __restrict__ A, const u16* __restrict__ Bt,
                 const float* __restrict__ bias, void* __restrict__ Cout,
                 int N, int K, int gx, u16* __restrict__ vt,
                 const void* __restrict__ resid) {
  constexpr int ABYTES = BM * 64;          // A bytes per buffer (BM x 32 bf16)
  constexpr int BUFSZ = ABYTES + 8192;     // + B (128 x 32 bf16)
  __shared__ char lds[3 * BUFSZ];
  const int tid = threadIdx.x;
  const int wave = tid >> 6, lane = tid & 63;
  const int lr = lane & 15, lg = lane >> 4;
  const int wr = wave >> 1, wc = wave & 1;

  const int kk = blockIdx.x >> 3, xcd = blockIdx.x & 7;
  const int row0 = (xcd + 8 * (kk / gx)) * BM, col0 = (kk % gx) * 128;

  size_t aofs[2], bofs[2];
#pragma unroll
  for (int i = 0; i < 2; ++i) {
    int r, s;
    inv_swz(tid + i * (BM * 2), r, s);
    aofs[i] = (size_t)(row0 + r) * K + s * 8;
  }
  {
    int r, s;
    inv_swz(tid, r, s);
    bofs[0] = (size_t)(col0 + r) * K + s * 8;
    if (BM == 128) {
      inv_swz(tid + 256, r, s);
      bofs[1] = (size_t)(col0 + r) * K + s * 8;
    }
  }
  const int aD0 = wave * 1024, aD1 = BM * 32 + wave * 1024;

  int aB[4], bB[4];
#pragma unroll
  for (int mi = 0; mi < 4; ++mi) {
    int row = wr * 64 + mi * 16 + lr;
    aB[mi] = ((row << 6) | (lg << 4)) ^ ((row & 7) << 4);
  }
#pragma unroll
  for (int nj = 0; nj < 4; ++nj) {
    int row = wc * 64 + nj * 16 + lr;
    bB[nj] = ((row << 6) | (lg << 4)) ^ ((row & 7) << 4);
  }

  f32x4 acc[4][4];
#pragma unroll
  for (int i = 0; i < 4; ++i)
#pragma unroll
    for (int j = 0; j < 4; ++j) acc[i][j] = (f32x4){0.f, 0.f, 0.f, 0.f};

  const int NT = K >> 5;
  auto stage = [&](char* buf, int kb) {
    glds16(A + aofs[0] + kb, buf + aD0);
    glds16(A + aofs[1] + kb, buf + aD1);
    glds16(Bt + bofs[0] + kb, buf + ABYTES + wave * 1024);
    if (BM == 128)
      glds16(Bt + bofs[1] + kb, buf + ABYTES + 4096 + wave * 1024);
  };

  char* b0 = lds;
  char* b1 = lds + BUFSZ;
  char* b2 = lds + 2 * BUFSZ;
  stage(b0, 0);
  stage(b1, 32);
  for (int t = 0; t < NT; ++t) {
    if (t < NT - 1) {
      if (BM == 256) WAITV(3); else WAITV(4);
    } else {
      WAITV(0);
    }
    barf();
    if (t + 2 < NT) stage(b2, (t + 2) * 32);
    short8 a_[4], b_[4];
#pragma unroll
    for (int mi = 0; mi < 4; ++mi)
      a_[mi] = *(const short8*)(b0 + aB[mi]);
#pragma unroll
    for (int nj = 0; nj < 4; ++nj)
      b_[nj] = *(const short8*)(b0 + ABYTES + bB[nj]);
    __builtin_amdgcn_s_setprio(1);
#pragma unroll
    for (int mi = 0; mi < 4; ++mi)
#pragma unroll
      for (int nj = 0; nj < 4; ++nj)
        acc[mi][nj] = mfma16(a_[mi], b_[nj], acc[mi][nj]);
    __builtin_amdgcn_s_setprio(0);
    char* tmp = b0; b0 = b1; b1 = b2; b2 = tmp;
  }

  if (VFUSE && col0 >= 1536) {
#pragma unroll
    for (int mi = 0; mi < 4; ++mi) {
      int row = row0 + wr * 64 + mi * 16 + lg * 4;
      int b = row >> 11, s = row & 2047;
#pragma unroll
      for (int nj = 0; nj < 4; ++nj) {
        int col = col0 + wc * 64 + nj * 16 + lr;
        int bh = b * Hn + ((col - 1536) >> 6), dk = col & 63;
        s16x4 v;
#pragma unroll
        for (int r = 0; r < 4; ++r) v[r] = (short)f2bf(acc[mi][nj][r]);
        *(s16x4*)(vt + (size_t)(bh * 64 + dk) * Sn + s) = v;
      }
    }
    return;
  }

#pragma unroll
  for (int mi = 0; mi < 4; ++mi) {
    int row = row0 + wr * 64 + mi * 16 + lg * 4;
#pragma unroll
    for (int nj = 0; nj < 4; ++nj) {
      int col = col0 + wc * 64 + nj * 16 + lr;
      float bv = HAS_BIAS ? bias[col] : 0.f;
#pragma unroll
      for (int r = 0; r < 4; ++r) {
        float v = acc[mi][nj][r] + bv;
        size_t o = (size_t)(row + r) * N + col;
        if (RES == 1) v += ((const float*)resid)[o];
        if (RES == 2) v += bf2f(((const u16*)resid)[o]);
        if (RELU) v = fmaxf(v, 0.f);
        if (OUT_BF16) ((u16*)Cout)[o] = f2bf(v);
        else ((float*)Cout)[o] = v;
      }
    }
  }
}

// ---------------- flash attention (R10 version, frozen) ----------------
// 128 q-rows/block; static-shift softmax; K/V fragments read once per tile;
// l on the matrix pipe (MFMA vs all-ones).

__global__ __launch_bounds__(256, 3)
void attn_kernel(const u16* __restrict__ qkv, const u16* __restrict__ vt,
                 const int* __restrict__ mask, u16* __restrict__ ctx) {
  __shared__ u16 kbuf[2][4096];
  __shared__ u16 vbuf[2][4096];
  __shared__ u16 pbuf[4][2][1024];

  const int tid = threadIdx.x;
  const int wave = tid >> 6, lane = tid & 63;
  const int lr = lane & 15, lg = lane >> 4;

  const int lin = blockIdx.x;
  const int logical = (lin & 7) * 96 + (lin >> 3);
  const int qt = logical & 15;
  const int bh = logical >> 4;
  const int b = bh / Hn, h = bh % Hn;

  int ok;
  {
    const int4v* ms = (const int4v*)(mask + b * Sn);
    int4v m0 = ms[tid * 2], m1 = ms[tid * 2 + 1];
    ok = m0[0] && m0[1] && m0[2] && m0[3] && m1[0] && m1[1] && m1[2] && m1[3];
  }
  const bool allones = (__syncthreads_and(ok) != 0);

  const int cu = (lane & 7) ^ (lane >> 3);
  const int r0 = wave * 16 + (lane >> 3);
  const u16* kg0 = qkv + (size_t)(b * Sn + r0) * 2304 + 768 + h * 64 + cu * 8;
  const u16* vg0 = vt + (size_t)(bh * 64 + r0) * Sn + cu * 8;
  u16* kd = &kbuf[0][0] + wave * 1024;
  u16* vd = &vbuf[0][0] + wave * 1024;

  const size_t qrowA = (size_t)(b * Sn + qt * 128 + wave * 16 + lr) * 2304 + h * 64 + lg * 8;
  short8 qa0 = *(const short8*)(qkv + qrowA);
  short8 qa1 = *(const short8*)(qkv + qrowA + 32);
  const size_t qrowB = qrowA + (size_t)64 * 2304;
  short8 qb0 = *(const short8*)(qkv + qrowB);
  short8 qb1 = *(const short8*)(qkv + qrowB + 32);

  short8 ones;
#pragma unroll
  for (int j = 0; j < 8; ++j) ones[j] = (short)0x3F80;   // bf16 1.0

  const int rlo = (lg ^ (lr & 7)) << 4;
  const int rhi = ((4 + lg) ^ (lr & 7)) << 4;
  const int rowb = lr * 128;

  f32x4 caccA[4], caccB[4], laccA, laccB;
#pragma unroll
  for (int i = 0; i < 4; ++i) {
    caccA[i] = (f32x4){0.f, 0.f, 0.f, 0.f};
    caccB[i] = (f32x4){0.f, 0.f, 0.f, 0.f};
  }
  laccA = (f32x4){0.f, 0.f, 0.f, 0.f};
  laccB = (f32x4){0.f, 0.f, 0.f, 0.f};

  u16* pwA = &pbuf[wave][0][0];
  u16* pwB = &pbuf[wave][1][0];
  const int pwr = (lg >> 1), pwo = 8 * (lg & 1);

  auto stage = [&](int bf, int c) {
    const u16* kg = kg0 + (size_t)c * 64 * 2304;
    const u16* vg = vg0 + c * 64;
    glds16(kg,            kd + bf * 4096);
    glds16(kg + 8 * 2304, kd + bf * 4096 + 512);
    glds16(vg,            vd + bf * 4096);
    glds16(vg + 8 * Sn,   vd + bf * 4096 + 512);
  };

  stage(0, 0);
  __syncthreads();
  int cur = 0;
  for (int c = 0; c < 32; ++c) {
    if (c + 1 < 32) stage(cur ^ 1, c + 1);
    const char* kb = (const char*)&kbuf[cur][0];
    const char* vb = (const char*)&vbuf[cur][0];

    int4v mk[4];
    if (!allones) {
      const int4v* mp = (const int4v*)(mask + b * Sn + c * 64 + lg * 4);
#pragma unroll
      for (int f = 0; f < 4; ++f) mk[f] = mp[f * 4];
    }

    // QK^T both q-sets, each K fragment read once
    f32x4 scA[4], scB[4];
#pragma unroll
    for (int f = 0; f < 4; ++f) {
      short8 k0 = *(const short8*)(kb + f * 2048 + rowb + rlo);
      short8 k1 = *(const short8*)(kb + f * 2048 + rowb + rhi);
      f32x4 zA = (f32x4){-SHIFT, -SHIFT, -SHIFT, -SHIFT};
      zA = mfma16(k0, qa0, zA);
      zA = mfma16(k1, qa1, zA);
      scA[f] = zA;
      f32x4 zB = (f32x4){-SHIFT, -SHIFT, -SHIFT, -SHIFT};
      zB = mfma16(k0, qb0, zB);
      zB = mfma16(k1, qb1, zB);
      scB[f] = zB;
    }
    if (!allones) {
#pragma unroll
      for (int f = 0; f < 4; ++f)
#pragma unroll
        for (int r = 0; r < 4; ++r) {
          scA[f][r] = mk[f][r] ? scA[f][r] : -1.0e5f;
          scB[f][r] = mk[f][r] ? scB[f][r] : -1.0e5f;
        }
    }
#pragma unroll
    for (int f = 0; f < 4; ++f) {
#pragma unroll
      for (int r = 0; r < 4; ++r) {
        scA[f][r] = exp2_raw(scA[f][r]);
        scB[f][r] = exp2_raw(scB[f][r]);
      }
    }
    // P -> bf16 -> per-wave swizzled LDS (both sets), then read fragments
#pragma unroll
    for (int f = 0; f < 4; ++f) {
      u32x2 wA, wB;
      wA[0] = pk_bf16(scA[f][0], scA[f][1]);
      wA[1] = pk_bf16(scA[f][2], scA[f][3]);
      wB[0] = pk_bf16(scB[f][0], scB[f][1]);
      wB[1] = pk_bf16(scB[f][2], scB[f][3]);
      const int po = rowb + (((2 * f + pwr) ^ (lr & 7)) << 4) + pwo;
      *(u32x2*)((char*)pwA + po) = wA;
      *(u32x2*)((char*)pwB + po) = wB;
    }
    short8 pfA0 = *(const short8*)((const char*)pwA + rowb + rlo);
    short8 pfA1 = *(const short8*)((const char*)pwA + rowb + rhi);
    short8 pfB0 = *(const short8*)((const char*)pwB + rowb + rlo);
    short8 pfB1 = *(const short8*)((const char*)pwB + rowb + rhi);

    // PV both q-sets, each V fragment read once
#pragma unroll
    for (int fd = 0; fd < 4; ++fd) {
      short8 v0 = *(const short8*)(vb + fd * 2048 + rowb + rlo);
      short8 v1 = *(const short8*)(vb + fd * 2048 + rowb + rhi);
      caccA[fd] = mfma16(pfA0, v0, caccA[fd]);
      caccA[fd] = mfma16(pfA1, v1, caccA[fd]);
      caccB[fd] = mfma16(pfB0, v0, caccB[fd]);
      caccB[fd] = mfma16(pfB1, v1, caccB[fd]);
    }
    // l row-sums on the matrix pipe (B = ones)
    laccA = mfma16(pfA0, ones, laccA);
    laccA = mfma16(pfA1, ones, laccA);
    laccB = mfma16(pfB0, ones, laccB);
    laccB = mfma16(pfB1, ones, laccB);
    __syncthreads();
    cur ^= 1;
  }

  float linvA[4], linvB[4];
#pragma unroll
  for (int r = 0; r < 4; ++r) {
    linvA[r] = 1.0f / laccA[r];
    linvB[r] = 1.0f / laccB[r];
  }
  const int orow = b * Sn + qt * 128 + wave * 16 + lg * 4;
#pragma unroll
  for (int fd = 0; fd < 4; ++fd) {
    int col = h * 64 + fd * 16 + lr;
#pragma unroll
    for (int r = 0; r < 4; ++r) {
      ctx[(size_t)(orow + r) * Dn + col] = f2bf(caccA[fd][r] * linvA[r]);
      ctx[(size_t)(orow + 64 + r) * Dn + col] = f2bf(caccB[fd][r] * linvB[r]);
    }
  }
}

// ---- LayerNorm: one wave per row; ASRC: 0=fp32 1=bf16 input ---------------

template<int ASRC>
__global__ __launch_bounds__(256)
void ln_kernel(const void* __restrict__ a,
               const float* __restrict__ alpha, const float* __restrict__ beta,
               float* __restrict__ outf, u16* __restrict__ outb) {
  const int wave = threadIdx.x >> 6, lane = threadIdx.x & 63;
  const size_t base = ((size_t)blockIdx.x * 4 + wave) * Dn;
  const int o = lane * 4;
  f32x4 v[3];
  float s = 0.f, q = 0.f;
#pragma unroll
  for (int j = 0; j < 3; ++j) {
    f32x4 x;
    if (ASRC == 0) {
      x = *(const f32x4*)((const float*)a + base + j * 256 + o);
    } else {
      s16x4 bb = *(const s16x4*)((const u16*)a + base + j * 256 + o);
#pragma unroll
      for (int k = 0; k < 4; ++k) x[k] = bf2f((u16)bb[k]);
    }
    v[j] = x;
    s += (x[0] + x[1]) + (x[2] + x[3]);
    q += (x[0] * x[0] + x[1] * x[1]) + (x[2] * x[2] + x[3] * x[3]);
  }
#pragma unroll
  for (int sh = 1; sh < 64; sh <<= 1) {
    s += __shfl_xor(s, sh, 64);
    q += __shfl_xor(q, sh, 64);
  }
  const float mean = s * (1.f / 768.f);
  float var = (q - 768.f * mean * mean) * (1.f / 767.f);
  var = fmaxf(var, 0.f);
  const float rden = 1.f / (sqrtf(var) + EPS);
#pragma unroll
  for (int j = 0; j < 3; ++j) {
    f32x4 al = *(const f32x4*)(alpha + j * 256 + o);
    f32x4 be = *(const f32x4*)(beta + j * 256 + o);
    f32x4 y;
#pragma unroll
    for (int k = 0; k < 4; ++k)
      y[k] = al[k] * (v[j][k] - mean) * rden + be[k];
    if (outf) *(f32x4*)(outf + base + j * 256 + o) = y;
    if (outb) {
      u32x2 w;
      w[0] = pk_bf16(y[0], y[1]);
      w[1] = pk_bf16(y[2], y[3]);
      *(u32x2*)(outb + base + j * 256 + o) = w;
    }
  }
}

// ---------------- launch ----------------

extern "C" void kernel_launch(void* const* d_in, const int* in_sizes, int n_in,
                              void* d_out, int out_size, void* d_ws, size_t ws_size,
                              hipStream_t stream) {
  (void)in_sizes; (void)n_in; (void)out_size; (void)ws_size;
  const float* x    = (const float*)d_in[0];
  const int*   mask = (const int*)d_in[1];
  const float* wq   = (const float*)d_in[2];
  const float* wk   = (const float*)d_in[3];
  const float* wv   = (const float*)d_in[4];
  const float* wo   = (const float*)d_in[5];
  const float* w1   = (const float*)d_in[6];
  const float* b1   = (const float*)d_in[7];
  const float* w2   = (const float*)d_in[8];
  const float* b2   = (const float*)d_in[9];
  const float* ln1a = (const float*)d_in[10];
  const float* ln1b = (const float*)d_in[11];
  const float* ln2a = (const float*)d_in[12];
  const float* ln2b = (const float*)d_in[13];
  float* out = (float*)d_out;

  char* ws = (char*)d_ws;
  size_t off = 0;
  auto alloc = [&](size_t bytes) -> void* {
    void* p = ws + off;
    off += (bytes + 255) & ~(size_t)255;
    return p;
  };
  u16* xb    = (u16*)alloc((size_t)BS * Dn * 2);      // reused as ctx later
  u16* wqkvT = (u16*)alloc((size_t)2304 * Dn * 2);
  u16* woT   = (u16*)alloc((size_t)Dn * Dn * 2);      // contiguous after wqkvT
  u16* w1T   = (u16*)alloc((size_t)DFFn * Dn * 2);
  u16* w2T   = (u16*)alloc((size_t)Dn * DFFn * 2);
  u16* qkv   = (u16*)alloc((size_t)BS * 2304 * 2);
  u16* vt    = (u16*)alloc((size_t)48 * 64 * Sn * 2);
  u16* x1b   = (u16*)alloc((size_t)BS * Dn * 2);
  u16* ff1   = (u16*)alloc((size_t)BS * DFFn * 2);
  u16* y16   = (u16*)alloc((size_t)BS * Dn * 2);      // bf16 LN inputs
  u16* ctx   = xb;
  (void)woT;

  dim3 blk256(256), blk512(512);
  prep_kernel<<<dim3(9984), blk256, 0, stream>>>(x, wq, wk, wv, wo, w1, w2,
                                                 xb, wqkvT, w1T, w2T);

  // qkv = xb @ [wq'|wk|wv]; V tiles fused-transposed into vt
  gemm_kernel<256, true, false, false, true, 0><<<dim3(576), blk512, 0, stream>>>(xb, wqkvT, nullptr, qkv, 2304, 768, 18, vt, nullptr);
  attn_kernel<<<dim3(768), blk256, 0, stream>>>(qkv, vt, mask, ctx);
  // y16 = bf16(ctx @ wo + x)   (residual fused, bf16 out)
  gemm_kernel<128, true, false, false, false, 1><<<dim3(384), blk256, 0, stream>>>(ctx, wqkvT + 3 * Dn * Dn, nullptr, y16, 768, 768, 6, nullptr, x);
  // x1 = LN(y16) -> bf16
  ln_kernel<1><<<dim3(BS / 4), blk256, 0, stream>>>(y16, ln1a, ln1b, nullptr, x1b);
  // ff1 = relu(x1 @ w1 + b1)
  gemm_kernel<256, true, true, true, false, 0><<<dim3(768), blk512, 0, stream>>>(x1b, w1T, b1, ff1, 3072, 768, 24, nullptr, nullptr);
  // y16 = bf16(ff1 @ w2 + b2 + x1)   (residual fused, bf16 out)
  gemm_kernel<128, true, false, true, false, 2><<<dim3(384), blk256, 0, stream>>>(ff1, w2T, b2, y16, 768, 3072, 6, nullptr, x1b);
  // out = LN(y16)
  ln_kernel<1><<<dim3(BS / 4), blk256, 0, stream>>>(y16, ln2a, ln2b, out, nullptr);
}